// Round 8
// baseline (50.866 us; speedup 1.0000x reference)
//
#include <hip/hip_runtime.h>
#include <math.h>

// Problem constants: B=32, S=8192, D=256, f32 in/out.
constexpr int NB  = 32;
constexpr int NS  = 8192;
constexpr int ND  = 256;
constexpr int BPB = 64;                  // blocks per batch (k1)
constexpr int RPB = NS / BPB;            // 128 rows per block
constexpr int NWAVES = 4;                // 256 threads
constexpr int RBATCH = 8;                // rows per wave-iteration (2 slots x 4 rows)
constexpr int NITER  = RPB / (NWAVES * RBATCH);  // 4
constexpr int PSTRIDE = ND + 2;          // o[256], m, l
constexpr int NPART = NWAVES * 4;        // 16 lane-group partials per block
constexpr int K2PB = 8;                  // k2 blocks per batch

// Kernel 1: one pass over `sequence`. 16-lanes-per-row decomposition (R7):
// lane (g = lane>>4, q = lane&15) owns row-elements [16q, 16q+16) — a fully
// contiguous 64 B per lane, 4x dwordx4. The wave covers 4 rows (g=0..3) per
// slot, 2 slots per 8-row group. Butterfly is 4 steps within the 16-lane
// group (8 DS insts/group vs 20 before); each group's online-softmax state
// covers only its own rows, so no cross-row max tree and only 3 exps/group.
// Static register double-buffer prefetch of the next group's loads.
// NOTE (R4): plain loads, NOT nontemporal — nt cost ~11% stream BW.
// NOTE (R6): NO device-scope fence/atomic epilogue — L2-flush per block
// collapses stream BW 20x on multi-XCD CDNA4.
__global__ __launch_bounds__(256) void k1_partial(
    const float* __restrict__ seq,
    const float* __restrict__ vec,
    const float* __restrict__ mask,
    float* __restrict__ scores,     // d_out + NB*ND (attn region, raw scores)
    float* __restrict__ partials)   // [NB*BPB][PSTRIDE]
{
    const int blk   = blockIdx.x;
    const int b     = blk / BPB;
    const int chunk = blk % BPB;
    const int tid   = threadIdx.x;
    const int lane  = tid & 63;
    const int wave  = tid >> 6;
    const int g     = lane >> 4;    // row-group id (0..3)
    const int q     = lane & 15;    // sublane within group

    // v fragment: elements [16q, 16q+16)
    const float* vb = vec + b * ND + q * 16;
    float4 v[4];
    #pragma unroll
    for (int j = 0; j < 4; ++j)
        v[j] = *reinterpret_cast<const float4*>(vb + j * 4);

    float  m = -1e30f;   // finite sentinel (unmasked max, per reference)
    float  l = 0.f;
    float4 o[4];
    #pragma unroll
    for (int j = 0; j < 4; ++j) o[j] = make_float4(0.f, 0.f, 0.f, 0.f);

    const int row0 = chunk * RPB;
    const float* __restrict__ seqb   = seq  + (size_t)b * NS * ND;
    const float* __restrict__ maskb  = mask + (size_t)b * NS;
    float* __restrict__       scoreb = scores + (size_t)b * NS;

    const int    sbase  = row0 + wave * RBATCH;       // wave's first row this iter
    const size_t rowoff = (size_t)g * ND;             // my group's row offset
    const float* base   = seqb + (size_t)sbase * ND + q * 16;

    float4 xa0[4], xa1[4], xb0[4], xb1[4];   // dbuf: slot0/slot1 x 4 float4

    auto LOAD = [&](float4 (&x0)[4], float4 (&x1)[4], int it) {
        const float* p = base + (size_t)it * (NWAVES * RBATCH) * ND + rowoff;
        #pragma unroll
        for (int j = 0; j < 4; ++j) {
            x0[j] = *reinterpret_cast<const float4*>(p + j * 4);
            x1[j] = *reinterpret_cast<const float4*>(p + (size_t)4 * ND + j * 4);
        }
    };

    auto PROC = [&](const float4 (&x0)[4], const float4 (&x1)[4], int it) {
        float dot0 = 0.f, dot1 = 0.f;
        #pragma unroll
        for (int j = 0; j < 4; ++j) {
            dot0 += x0[j].x * v[j].x + x0[j].y * v[j].y + x0[j].z * v[j].z + x0[j].w * v[j].w;
            dot1 += x1[j].x * v[j].x + x1[j].y * v[j].y + x1[j].z * v[j].z + x1[j].w * v[j].w;
        }
        // 4-step butterfly within the 16-lane group (2 independent chains)
        #pragma unroll
        for (int off = 1; off < 16; off <<= 1) {
            dot0 += __shfl_xor(dot0, off, 64);
            dot1 += __shfl_xor(dot1, off, 64);
        }
        const int s = sbase + it * (NWAVES * RBATCH);
        if (q == 0) {
            scoreb[s + g]     = dot0;
            scoreb[s + 4 + g] = dot1;
        }
        const float mk0 = maskb[s + g];
        const float mk1 = maskb[s + 4 + g];

        const float mn    = fmaxf(m, fmaxf(dot0, dot1));  // this group's rows only
        const float scale = __expf(m - mn);
        const float e0 = __expf(dot0 - mn) * mk0;
        const float e1 = __expf(dot1 - mn) * mk1;
        l = l * scale + e0 + e1;
        #pragma unroll
        for (int j = 0; j < 4; ++j) {
            o[j].x = o[j].x * scale + e0 * x0[j].x + e1 * x1[j].x;
            o[j].y = o[j].y * scale + e0 * x0[j].y + e1 * x1[j].y;
            o[j].z = o[j].z * scale + e0 * x0[j].z + e1 * x1[j].z;
            o[j].w = o[j].w * scale + e0 * x0[j].w + e1 * x1[j].w;
        }
        m = mn;
    };

    LOAD(xa0, xa1, 0);
    #pragma unroll
    for (int it = 0; it < NITER; ++it) {
        if ((it & 1) == 0) {
            if (it + 1 < NITER) LOAD(xb0, xb1, it + 1);
            PROC(xa0, xa1, it);
        } else {
            if (it + 1 < NITER) LOAD(xa0, xa1, it + 1);
            PROC(xb0, xb1, it);
        }
    }

    // combine the 16 lane-group partials within the block
    __shared__ float so[NPART][ND];   // 16 KiB
    __shared__ float sml[NPART][2];
    const int u = wave * 4 + g;
    #pragma unroll
    for (int j = 0; j < 4; ++j)
        *reinterpret_cast<float4*>(&so[u][q * 16 + j * 4]) = o[j];
    if (q == 0) { sml[u][0] = m; sml[u][1] = l; }
    __syncthreads();

    float M = sml[0][0];
    #pragma unroll
    for (int i = 1; i < NPART; ++i) M = fmaxf(M, sml[i][0]);
    float L = 0.f, O = 0.f;
    #pragma unroll
    for (int i = 0; i < NPART; ++i) {
        const float wgt = __expf(sml[i][0] - M);
        L += sml[i][1] * wgt;
        O += so[i][tid] * wgt;
    }
    float* p = partials + (size_t)blk * PSTRIDE;
    p[tid] = O;
    if (tid == 0) { p[ND] = M; p[ND + 1] = L; }
}

// Kernel 2 (fused reduce+normalize): 8 blocks per batch. Every block
// redundantly recomputes the per-batch (M, L) from the 64 partial (m,l)
// pairs; block j==0 additionally reduces the 64 O-partials into `pooled`;
// all 8 blocks normalize a 1/8 slice of the raw scores into attn.
__global__ __launch_bounds__(256) void k2_fused(
    const float* __restrict__ partials,
    const float* __restrict__ mask,
    float* __restrict__ pooled,     // d_out [NB][ND]
    float* __restrict__ attn)       // d_out + NB*ND [NB][NS]
{
    const int b   = blockIdx.x >> 3;
    const int j   = blockIdx.x & (K2PB - 1);
    const int tid = threadIdx.x;
    __shared__ float w[BPB];
    __shared__ float sM, sL;
    const float* __restrict__ pb = partials + (size_t)b * BPB * PSTRIDE;

    if (tid < BPB) {   // wave 0 exactly (BPB == 64)
        const float mi = pb[tid * PSTRIDE + ND];
        float M = mi;
        #pragma unroll
        for (int off = 32; off > 0; off >>= 1)
            M = fmaxf(M, __shfl_xor(M, off, 64));
        const float li = pb[tid * PSTRIDE + ND + 1];
        const float wi = __expf(mi - M);
        w[tid] = wi;
        float L = li * wi;
        #pragma unroll
        for (int off = 32; off > 0; off >>= 1)
            L += __shfl_xor(L, off, 64);
        if (tid == 0) { sM = M; sL = L; }
    }
    __syncthreads();

    const float M  = sM;
    const float rL = 1.0f / (sL + 1e-13f);

    if (j == 0) {
        float acc = 0.f;
        #pragma unroll 8
        for (int i = 0; i < BPB; ++i)
            acc += pb[i * PSTRIDE + tid] * w[i];
        pooled[b * ND + tid] = acc * rL;
    }

    // normalize this block's 1/8 slice of the batch row: 1024 floats
    const int s0 = j * (NS / K2PB) + tid * 4;
    float* ap = attn + (size_t)b * NS + s0;
    const float* mp = mask + (size_t)b * NS + s0;
    float4 sc = *reinterpret_cast<float4*>(ap);
    const float4 mk = *reinterpret_cast<const float4*>(mp);
    sc.x = __expf(sc.x - M) * mk.x * rL;
    sc.y = __expf(sc.y - M) * mk.y * rL;
    sc.z = __expf(sc.z - M) * mk.z * rL;
    sc.w = __expf(sc.w - M) * mk.w * rL;
    *reinterpret_cast<float4*>(ap) = sc;
}

extern "C" void kernel_launch(void* const* d_in, const int* in_sizes, int n_in,
                              void* d_out, int out_size, void* d_ws, size_t ws_size,
                              hipStream_t stream)
{
    const float* seq  = (const float*)d_in[0];   // [B, S, D]
    const float* vec  = (const float*)d_in[1];   // [B, D]
    const float* mask = (const float*)d_in[2];   // [B, S]

    float* pooled = (float*)d_out;               // [B, D]
    float* attn   = pooled + NB * ND;            // [B, S]

    float* partials = (float*)d_ws;              // 2048 * 258 * 4 B ~= 2.1 MiB

    k1_partial<<<NB * BPB, 256, 0, stream>>>(seq, vec, mask, attn, partials);
    k2_fused<<<NB * K2PB, 256, 0, stream>>>(partials, mask, pooled, attn);
}

// Round 9
// 49.712 us; speedup vs baseline: 1.0232x; 1.0232x over previous
//
#include <hip/hip_runtime.h>
#include <math.h>

// Problem constants: B=32, S=8192, D=256, f32 in/out.
constexpr int NB  = 32;
constexpr int NS  = 8192;
constexpr int ND  = 256;
constexpr int BPB = 64;                  // blocks per batch (k1)
constexpr int RPB = NS / BPB;            // 128 rows per block
constexpr int NWAVES = 4;                // 256 threads
constexpr int RBATCH = 8;                // rows per wave-iteration (4 per half-wave)
constexpr int NITER  = RPB / (NWAVES * RBATCH);  // 4
constexpr int PSTRIDE = ND + 2;          // o[256], m, l
constexpr int NPART = NWAVES * 2;        // 8 half-wave partials per block
constexpr int K2PB = 8;                  // k2 blocks per batch
constexpr int HD = ND / 2;               // 128: half-row element count

// Kernel 1 (R7 best, 49.8 us): one pass over `sequence`. Half-wave
// decomposition: 32 lanes own one row; lane sl owns elements [4sl,4sl+4) of
// the row's first half and [128+4sl,...) of the second half — each dwordx4
// covers fully-contiguous 512 B across the half-wave. 5-step butterfly
// dot-reduce, 4 exps/lane per 8-row group, one online rescale per group
// (exact). Static register double-buffer prefetch.
// NOTE (R4): plain loads, NOT nontemporal — nt cost ~11% stream BW.
// NOTE (R6): NO device-scope fence/atomic epilogue — L2-flush per block
// collapses stream BW 20x on multi-XCD CDNA4.
// NOTE (R8): 16-lane-per-row variant (fewer DS/exp ops) regressed — issue
// pressure is NOT the limiter; this structure is at the stream ceiling.
__global__ __launch_bounds__(256) void k1_partial(
    const float* __restrict__ seq,
    const float* __restrict__ vec,
    const float* __restrict__ mask,
    float* __restrict__ scores,     // d_out + NB*ND (attn region, raw scores)
    float* __restrict__ partials)   // [NB*BPB][PSTRIDE]
{
    const int blk   = blockIdx.x;
    const int b     = blk / BPB;
    const int chunk = blk % BPB;
    const int tid   = threadIdx.x;
    const int lane  = tid & 63;
    const int wave  = tid >> 6;
    const int h     = lane >> 5;    // half-wave id
    const int sl    = lane & 31;    // sublane within half

    const float* vb = vec + b * ND + sl * 4;
    const float4 v0 = *reinterpret_cast<const float4*>(vb);
    const float4 v1 = *reinterpret_cast<const float4*>(vb + HD);

    float  m = -1e30f;   // finite sentinel (unmasked max, per reference)
    float  l = 0.f;
    float4 o0 = make_float4(0.f, 0.f, 0.f, 0.f);
    float4 o1 = make_float4(0.f, 0.f, 0.f, 0.f);

    const int row0 = chunk * RPB;
    const float* __restrict__ seqb   = seq  + (size_t)b * NS * ND;
    const float* __restrict__ maskb  = mask + (size_t)b * NS;
    float* __restrict__       scoreb = scores + (size_t)b * NS;

    const int   sbase = row0 + wave * RBATCH + h * 4;
    const float* base = seqb + (size_t)sbase * ND + sl * 4;

    float4 xa0[4], xa1[4], xb0[4], xb1[4];   // double-buffered: 4 rows x 8 floats

    auto LOAD = [&](float4 (&x0)[4], float4 (&x1)[4], int it) {
        const float* p = base + (size_t)it * (NWAVES * RBATCH) * ND;
        #pragma unroll
        for (int k = 0; k < 4; ++k) {
            x0[k] = *reinterpret_cast<const float4*>(p + (size_t)k * ND);
            x1[k] = *reinterpret_cast<const float4*>(p + (size_t)k * ND + HD);
        }
    };

    auto PROC = [&](const float4 (&x0)[4], const float4 (&x1)[4], int it) {
        float dot[4];
        #pragma unroll
        for (int k = 0; k < 4; ++k)
            dot[k] = x0[k].x * v0.x + x0[k].y * v0.y + x0[k].z * v0.z + x0[k].w * v0.w
                   + x1[k].x * v1.x + x1[k].y * v1.y + x1[k].z * v1.z + x1[k].w * v1.w;
        #pragma unroll
        for (int off = 1; off < 32; off <<= 1) {
            #pragma unroll
            for (int k = 0; k < 4; ++k)
                dot[k] += __shfl_xor(dot[k], off, 64);
        }
        const int s0h = sbase + it * (NWAVES * RBATCH);
        if (sl == 0)
            *reinterpret_cast<float4*>(scoreb + s0h) =
                make_float4(dot[0], dot[1], dot[2], dot[3]);
        const float4 mk = *reinterpret_cast<const float4*>(maskb + s0h);

        const float mx = fmaxf(fmaxf(dot[0], dot[1]), fmaxf(dot[2], dot[3]));
        const float mn = fmaxf(m, mx);
        const float scale = __expf(m - mn);
        float e[4];
        e[0] = __expf(dot[0] - mn) * mk.x;
        e[1] = __expf(dot[1] - mn) * mk.y;
        e[2] = __expf(dot[2] - mn) * mk.z;
        e[3] = __expf(dot[3] - mn) * mk.w;
        l    = l    * scale + e[0] + e[1] + e[2] + e[3];
        o0.x = o0.x * scale; o0.y = o0.y * scale; o0.z = o0.z * scale; o0.w = o0.w * scale;
        o1.x = o1.x * scale; o1.y = o1.y * scale; o1.z = o1.z * scale; o1.w = o1.w * scale;
        #pragma unroll
        for (int k = 0; k < 4; ++k) {
            o0.x += e[k] * x0[k].x; o0.y += e[k] * x0[k].y;
            o0.z += e[k] * x0[k].z; o0.w += e[k] * x0[k].w;
            o1.x += e[k] * x1[k].x; o1.y += e[k] * x1[k].y;
            o1.z += e[k] * x1[k].z; o1.w += e[k] * x1[k].w;
        }
        m = mn;
    };

    LOAD(xa0, xa1, 0);
    #pragma unroll
    for (int it = 0; it < NITER; ++it) {
        if ((it & 1) == 0) {
            if (it + 1 < NITER) LOAD(xb0, xb1, it + 1);
            PROC(xa0, xa1, it);
        } else {
            if (it + 1 < NITER) LOAD(xa0, xa1, it + 1);
            PROC(xb0, xb1, it);
        }
    }

    // combine the 8 half-wave partials within the block (element-position LDS)
    __shared__ float so[NPART][ND];   // 8 KiB
    __shared__ float sml[NPART][2];
    const int u = wave * 2 + h;
    *reinterpret_cast<float4*>(&so[u][sl * 4])      = o0;
    *reinterpret_cast<float4*>(&so[u][HD + sl * 4]) = o1;
    if (sl == 0) { sml[u][0] = m; sml[u][1] = l; }
    __syncthreads();

    float M = sml[0][0];
    #pragma unroll
    for (int i = 1; i < NPART; ++i) M = fmaxf(M, sml[i][0]);
    float L = 0.f, O = 0.f;
    #pragma unroll
    for (int i = 0; i < NPART; ++i) {
        const float wgt = __expf(sml[i][0] - M);
        L += sml[i][1] * wgt;
        O += so[i][tid] * wgt;
    }
    float* p = partials + (size_t)blk * PSTRIDE;
    p[tid] = O;
    if (tid == 0) { p[ND] = M; p[ND + 1] = L; }
}

// Kernel 2 (fused reduce+normalize): 8 blocks per batch. Every block
// redundantly recomputes the per-batch (M, L) from the 64 partial (m,l)
// pairs; block j==0 additionally reduces the 64 O-partials into `pooled`;
// all 8 blocks normalize a 1/8 slice of the raw scores into attn.
__global__ __launch_bounds__(256) void k2_fused(
    const float* __restrict__ partials,
    const float* __restrict__ mask,
    float* __restrict__ pooled,     // d_out [NB][ND]
    float* __restrict__ attn)       // d_out + NB*ND [NB][NS]
{
    const int b   = blockIdx.x >> 3;
    const int j   = blockIdx.x & (K2PB - 1);
    const int tid = threadIdx.x;
    __shared__ float w[BPB];
    __shared__ float sM, sL;
    const float* __restrict__ pb = partials + (size_t)b * BPB * PSTRIDE;

    if (tid < BPB) {   // wave 0 exactly (BPB == 64)
        const float mi = pb[tid * PSTRIDE + ND];
        float M = mi;
        #pragma unroll
        for (int off = 32; off > 0; off >>= 1)
            M = fmaxf(M, __shfl_xor(M, off, 64));
        const float li = pb[tid * PSTRIDE + ND + 1];
        const float wi = __expf(mi - M);
        w[tid] = wi;
        float L = li * wi;
        #pragma unroll
        for (int off = 32; off > 0; off >>= 1)
            L += __shfl_xor(L, off, 64);
        if (tid == 0) { sM = M; sL = L; }
    }
    __syncthreads();

    const float M  = sM;
    const float rL = 1.0f / (sL + 1e-13f);

    if (j == 0) {
        float acc = 0.f;
        #pragma unroll 8
        for (int i = 0; i < BPB; ++i)
            acc += pb[i * PSTRIDE + tid] * w[i];
        pooled[b * ND + tid] = acc * rL;
    }

    // normalize this block's 1/8 slice of the batch row: 1024 floats
    const int s0 = j * (NS / K2PB) + tid * 4;
    float* ap = attn + (size_t)b * NS + s0;
    const float* mp = mask + (size_t)b * NS + s0;
    float4 sc = *reinterpret_cast<float4*>(ap);
    const float4 mk = *reinterpret_cast<const float4*>(mp);
    sc.x = __expf(sc.x - M) * mk.x * rL;
    sc.y = __expf(sc.y - M) * mk.y * rL;
    sc.z = __expf(sc.z - M) * mk.z * rL;
    sc.w = __expf(sc.w - M) * mk.w * rL;
    *reinterpret_cast<float4*>(ap) = sc;
}

extern "C" void kernel_launch(void* const* d_in, const int* in_sizes, int n_in,
                              void* d_out, int out_size, void* d_ws, size_t ws_size,
                              hipStream_t stream)
{
    const float* seq  = (const float*)d_in[0];   // [B, S, D]
    const float* vec  = (const float*)d_in[1];   // [B, D]
    const float* mask = (const float*)d_in[2];   // [B, S]

    float* pooled = (float*)d_out;               // [B, D]
    float* attn   = pooled + NB * ND;            // [B, S]

    float* partials = (float*)d_ws;              // 2048 * 258 * 4 B ~= 2.1 MiB

    k1_partial<<<NB * BPB, 256, 0, stream>>>(seq, vec, mask, attn, partials);
    k2_fused<<<NB * K2PB, 256, 0, stream>>>(partials, mask, pooled, attn);
}